// Round 4
// baseline (228.965 us; speedup 1.0000x reference)
//
#include <hip/hip_runtime.h>
#include <hip/hip_bf16.h>
#include <math.h>

// Problem dims (fixed by the reference): B=4096, M=2, D=2048
#define MROWS 8192   // B*M rows of the GEMM
#define KDIM  2048
#define NDIM  2048

#define BM 256
#define BN 128
#define BK 32        // double-buffered: 2 x (256+128)*32*2B = 48 KiB LDS

typedef short  v8s __attribute__((ext_vector_type(8)));   // 8 bf16 (4 VGPRs)
typedef float  v4f __attribute__((ext_vector_type(4)));   // MFMA acc

// workspace layout (bytes)
#define A_OFF   0ull
#define W_OFF   ((unsigned long long)MROWS * KDIM * 2ull)               // 32 MiB
#define MWZ_OFF (W_OFF + (unsigned long long)NDIM * KDIM * 2ull)        // +8 MiB

__device__ inline unsigned short f2bf(float f) {
    __hip_bfloat16 h = __float2bfloat16(f);   // RNE
    return *reinterpret_cast<unsigned short*>(&h);
}

// ---------------------------------------------------------------------------
// Prep: zeta scalar, A = bf16(x + emb[ids]), W = bf16(Wt)
// ---------------------------------------------------------------------------
__global__ __launch_bounds__(256) void prep_kernel(
    const float* __restrict__ x, const int* __restrict__ ids,
    const float* __restrict__ mw, const float* __restrict__ emb,
    const float* __restrict__ Wrc, const float* __restrict__ brc,
    const float* __restrict__ Wt,
    unsigned short* __restrict__ Abf, unsigned short* __restrict__ Wbf,
    float* __restrict__ mwz)
{
    const int tid = threadIdx.x;

    // zeta = sigmoid(0.2 * sum(Wrc) + brc); block 0 only
    if (blockIdx.x == 0) {
        __shared__ float red[256];
        float s = 0.f;
        for (int d = tid; d < KDIM; d += 256) s += Wrc[d];
        red[tid] = s;
        __syncthreads();
        for (int off = 128; off > 0; off >>= 1) {
            if (tid < off) red[tid] += red[tid + off];
            __syncthreads();
        }
        if (tid == 0) {
            float zeta = 1.0f / (1.0f + expf(-(0.2f * red[0] + brc[0])));
            mwz[0] = mw[0] * zeta;
            mwz[1] = mw[1] * zeta;
        }
    }

    // A conversion: 8 floats -> 8 bf16 per thread-iter
    const int groupsA = MROWS * KDIM / 8;
    for (int g = blockIdx.x * 256 + tid; g < groupsA; g += gridDim.x * 256) {
        const int row = g >> 8;            // 256 groups of 8 per 2048-row
        const int off = (g & 255) << 3;
        const int st  = ids[row];
        const float4* xp = (const float4*)(x   + (size_t)row * KDIM + off);
        const float4* ep = (const float4*)(emb + (size_t)st  * KDIM + off);
        float4 x0 = xp[0], x1 = xp[1];
        float4 e0 = ep[0], e1 = ep[1];
        v8s o;
        o[0] = (short)f2bf(x0.x + e0.x);
        o[1] = (short)f2bf(x0.y + e0.y);
        o[2] = (short)f2bf(x0.z + e0.z);
        o[3] = (short)f2bf(x0.w + e0.w);
        o[4] = (short)f2bf(x1.x + e1.x);
        o[5] = (short)f2bf(x1.y + e1.y);
        o[6] = (short)f2bf(x1.z + e1.z);
        o[7] = (short)f2bf(x1.w + e1.w);
        *(v8s*)(Abf + (size_t)g * 8) = o;
    }

    // W conversion
    const int groupsW = NDIM * KDIM / 8;
    for (int g = blockIdx.x * 256 + tid; g < groupsW; g += gridDim.x * 256) {
        const float4* wp = (const float4*)(Wt + (size_t)g * 8);
        float4 w0 = wp[0], w1 = wp[1];
        v8s o;
        o[0] = (short)f2bf(w0.x); o[1] = (short)f2bf(w0.y);
        o[2] = (short)f2bf(w0.z); o[3] = (short)f2bf(w0.w);
        o[4] = (short)f2bf(w1.x); o[5] = (short)f2bf(w1.y);
        o[6] = (short)f2bf(w1.z); o[7] = (short)f2bf(w1.w);
        *(v8s*)(Wbf + (size_t)g * 8) = o;
    }
}

// ---------------------------------------------------------------------------
// GEMM: out[r][n] = sum_k A[r][k] * W[n][k]  (W stored row-major = B^T form)
// 256x128 block, 4 waves 2(M)x2(N), each wave 128x64 = 8x4 MFMA 16x16x32.
// DOUBLE-BUFFERED K-loop (BK=32, ping-pong LDS, ONE barrier per iter):
//   barrier -> issue global_load_lds into buf_next -> compute buf_cur
// so staged loads are always one full compute phase in flight when drained.
// OPERAND SWAP: mfma(W_frag, A_frag) -> acc holds out^T; lane's 4 acc regs
// are 4 consecutive output columns at fixed row -> dwordx4 stores.
// ---------------------------------------------------------------------------
__global__ __launch_bounds__(256, 2) void gemm_kernel(
    const unsigned short* __restrict__ Abf,
    const unsigned short* __restrict__ Wbf,
    const float* __restrict__ bt,
    const float* __restrict__ mwz,
    float* __restrict__ out)
{
    // [2 buffers][tile]: A = 256x32, B = 128x32 bf16
    __shared__ __align__(16) unsigned short lA[2][BM * BK];  // 2 x 16 KiB
    __shared__ __align__(16) unsigned short lB[2][BN * BK];  // 2 x  8 KiB

    const int tid  = threadIdx.x;
    const int lane = tid & 63;
    const int wave = tid >> 6;
    const int wr   = wave & 1;        // wave M-half (0..1) -> 128 rows
    const int wc   = wave >> 1;       // wave N-half (0..1) -> 64 cols
    const int quad = lane >> 4;       // 0..3
    const int mcol = lane & 15;       // 0..15

    const int br = blockIdx.x;        // 32 row-blocks
    const int bc = blockIdx.y;        // 16 col-blocks

    v4f acc[8][4];
    const v4f vzero = {0.f, 0.f, 0.f, 0.f};
    #pragma unroll
    for (int i = 0; i < 8; i++)
        #pragma unroll
        for (int j = 0; j < 4; j++) acc[i][j] = vzero;

    const unsigned short* gA = Abf + (size_t)(br * BM) * KDIM;
    const unsigned short* gB = Wbf + (size_t)(bc * BN) * KDIM;

    // stage(kt -> buffer b): A 256x32 (4 issues), B 128x32 (2 issues)
    // LDS slot f holds row=f>>2, global chunk ch=(f&3)^(row&3) (fetch-side
    // XOR swizzle; global_load_lds dest is forced base+lane*16)
    #define STAGE(KT, BUF)                                                     \
        {                                                                      \
            const int kt_ = (KT);                                              \
            _Pragma("unroll")                                                  \
            for (int q = 0; q < 4; q++) {                                      \
                const int f   = q * 256 + tid;                                 \
                const int row = f >> 2;                                        \
                const int ch  = (f & 3) ^ (row & 3);                           \
                const unsigned short* ga = gA + (size_t)row * KDIM + kt_ + ch * 8; \
                __builtin_amdgcn_global_load_lds(                              \
                    (const __attribute__((address_space(1))) void*)ga,         \
                    (__attribute__((address_space(3))) void*)(&lA[BUF][(size_t)f * 8]), \
                    16, 0, 0);                                                 \
            }                                                                  \
            _Pragma("unroll")                                                  \
            for (int q = 0; q < 2; q++) {                                      \
                const int f   = q * 256 + tid;                                 \
                const int row = f >> 2;                                        \
                const int ch  = (f & 3) ^ (row & 3);                           \
                const unsigned short* gb = gB + (size_t)row * KDIM + kt_ + ch * 8; \
                __builtin_amdgcn_global_load_lds(                              \
                    (const __attribute__((address_space(1))) void*)gb,         \
                    (__attribute__((address_space(3))) void*)(&lB[BUF][(size_t)f * 8]), \
                    16, 0, 0);                                                 \
            }                                                                  \
        }

    STAGE(0, 0);   // prologue: first tile into buffer 0

    const int NITER = KDIM / BK;   // 64
    for (int it = 0; it < NITER; it++) {
        const int cur = it & 1;
        const int nxt = cur ^ 1;

        // barrier: (a) drains this wave's loads into buf_cur (compiler emits
        // vmcnt(0) before s_barrier); (b) all waves done reading buf_nxt from
        // iter it-1, so overwriting it below is safe.
        __syncthreads();

        if (it + 1 < NITER) STAGE((it + 1) * BK, nxt);

        // compute from buf_cur: one K=32 step, 8x4 tiles, 12 ds_read_b128
        v8s af[8], bf_[4];
        #pragma unroll
        for (int i = 0; i < 8; i++) {
            const int row = wr * 128 + i * 16 + mcol;      // A row (m)
            const int c   = quad ^ (row & 3);              // unswizzle
            af[i] = *(const v8s*)(&lA[cur][row * BK + c * 8]);
        }
        #pragma unroll
        for (int j = 0; j < 4; j++) {
            const int col = wc * 64 + j * 16 + mcol;       // B col (n)
            const int c   = quad ^ (col & 3);
            bf_[j] = *(const v8s*)(&lB[cur][col * BK + c * 8]);
        }
        // operand swap: D = W_frag x A_frag => acc is out^T tile:
        //   reg-index (quad*4+r) = output COLUMN, mcol = output ROW
        #pragma unroll
        for (int i = 0; i < 8; i++)
            #pragma unroll
            for (int j = 0; j < 4; j++)
                acc[i][j] = __builtin_amdgcn_mfma_f32_16x16x32_bf16(
                    bf_[j], af[i], acc[i][j], 0, 0, 0);
    }
    #undef STAGE

    // ---- epilogue: bias + relu + scale + relu, dwordx4 fp32 stores ----
    // row parity: all tile offsets even, so parity = mcol & 1
    const float mz = mwz[mcol & 1];
    #pragma unroll
    for (int j = 0; j < 4; j++) {
        const int ncol = bc * BN + wc * 64 + j * 16 + quad * 4;  // 4 consecutive cols
        const float4 b4 = *(const float4*)(bt + ncol);
        #pragma unroll
        for (int i = 0; i < 8; i++) {
            const int row = br * BM + wr * 128 + i * 16 + mcol;
            float4 o;
            o.x = fmaxf(mz * fmaxf(acc[i][j][0] + b4.x, 0.0f), 0.0f);
            o.y = fmaxf(mz * fmaxf(acc[i][j][1] + b4.y, 0.0f), 0.0f);
            o.z = fmaxf(mz * fmaxf(acc[i][j][2] + b4.z, 0.0f), 0.0f);
            o.w = fmaxf(mz * fmaxf(acc[i][j][3] + b4.w, 0.0f), 0.0f);
            *(float4*)(out + (size_t)row * NDIM + ncol) = o;
        }
    }
}

// ---------------------------------------------------------------------------
extern "C" void kernel_launch(void* const* d_in, const int* in_sizes, int n_in,
                              void* d_out, int out_size, void* d_ws, size_t ws_size,
                              hipStream_t stream) {
    const float* x    = (const float*)d_in[0];
    const int*   ids  = (const int*)  d_in[1];
    const float* mw   = (const float*)d_in[2];
    const float* emb  = (const float*)d_in[3];
    const float* Wt   = (const float*)d_in[4];
    const float* bt   = (const float*)d_in[5];
    const float* Wrc  = (const float*)d_in[6];
    const float* brc  = (const float*)d_in[7];
    float* out = (float*)d_out;

    char* ws = (char*)d_ws;
    unsigned short* Abf = (unsigned short*)(ws + A_OFF);
    unsigned short* Wbf = (unsigned short*)(ws + W_OFF);
    float* mwz          = (float*)(ws + MWZ_OFF);

    prep_kernel<<<2048, 256, 0, stream>>>(x, ids, mw, emb, Wrc, brc, Wt,
                                          Abf, Wbf, mwz);

    dim3 grid(MROWS / BM, NDIM / BN);   // 32 x 16 = 512 blocks = 2/CU exactly
    gemm_kernel<<<grid, 256, 0, stream>>>(Abf, Wbf, bt, mwz, out);
}

// Round 5
// 227.889 us; speedup vs baseline: 1.0047x; 1.0047x over previous
//
#include <hip/hip_runtime.h>
#include <hip/hip_bf16.h>
#include <math.h>

// Problem dims (fixed by the reference): B=4096, M=2, D=2048
#define MROWS 8192   // B*M rows of the GEMM
#define KDIM  2048
#define NDIM  2048

#define BM 256
#define BN 128
#define BK 32        // double-buffered: 2 x (256+128)*32*2B = 48 KiB LDS

typedef short  v8s __attribute__((ext_vector_type(8)));   // 8 bf16 (4 VGPRs)
typedef float  v4f __attribute__((ext_vector_type(4)));   // MFMA acc

// workspace layout (bytes)
#define A_OFF   0ull
#define W_OFF   ((unsigned long long)MROWS * KDIM * 2ull)               // 32 MiB
#define MWZ_OFF (W_OFF + (unsigned long long)NDIM * KDIM * 2ull)        // +8 MiB

__device__ inline unsigned short f2bf(float f) {
    __hip_bfloat16 h = __float2bfloat16(f);   // RNE
    return *reinterpret_cast<unsigned short*>(&h);
}

// ---------------------------------------------------------------------------
// Prep: zeta scalar, A = bf16(x + emb[ids]), W = bf16(Wt)
// ---------------------------------------------------------------------------
__global__ __launch_bounds__(256) void prep_kernel(
    const float* __restrict__ x, const int* __restrict__ ids,
    const float* __restrict__ mw, const float* __restrict__ emb,
    const float* __restrict__ Wrc, const float* __restrict__ brc,
    const float* __restrict__ Wt,
    unsigned short* __restrict__ Abf, unsigned short* __restrict__ Wbf,
    float* __restrict__ mwz)
{
    const int tid = threadIdx.x;

    // zeta = sigmoid(0.2 * sum(Wrc) + brc); block 0 only
    if (blockIdx.x == 0) {
        __shared__ float red[256];
        float s = 0.f;
        for (int d = tid; d < KDIM; d += 256) s += Wrc[d];
        red[tid] = s;
        __syncthreads();
        for (int off = 128; off > 0; off >>= 1) {
            if (tid < off) red[tid] += red[tid + off];
            __syncthreads();
        }
        if (tid == 0) {
            float zeta = 1.0f / (1.0f + expf(-(0.2f * red[0] + brc[0])));
            mwz[0] = mw[0] * zeta;
            mwz[1] = mw[1] * zeta;
        }
    }

    // A conversion: 8 floats -> 8 bf16 per thread-iter
    const int groupsA = MROWS * KDIM / 8;
    for (int g = blockIdx.x * 256 + tid; g < groupsA; g += gridDim.x * 256) {
        const int row = g >> 8;            // 256 groups of 8 per 2048-row
        const int off = (g & 255) << 3;
        const int st  = ids[row];
        const float4* xp = (const float4*)(x   + (size_t)row * KDIM + off);
        const float4* ep = (const float4*)(emb + (size_t)st  * KDIM + off);
        float4 x0 = xp[0], x1 = xp[1];
        float4 e0 = ep[0], e1 = ep[1];
        v8s o;
        o[0] = (short)f2bf(x0.x + e0.x);
        o[1] = (short)f2bf(x0.y + e0.y);
        o[2] = (short)f2bf(x0.z + e0.z);
        o[3] = (short)f2bf(x0.w + e0.w);
        o[4] = (short)f2bf(x1.x + e1.x);
        o[5] = (short)f2bf(x1.y + e1.y);
        o[6] = (short)f2bf(x1.z + e1.z);
        o[7] = (short)f2bf(x1.w + e1.w);
        *(v8s*)(Abf + (size_t)g * 8) = o;
    }

    // W conversion
    const int groupsW = NDIM * KDIM / 8;
    for (int g = blockIdx.x * 256 + tid; g < groupsW; g += gridDim.x * 256) {
        const float4* wp = (const float4*)(Wt + (size_t)g * 8);
        float4 w0 = wp[0], w1 = wp[1];
        v8s o;
        o[0] = (short)f2bf(w0.x); o[1] = (short)f2bf(w0.y);
        o[2] = (short)f2bf(w0.z); o[3] = (short)f2bf(w0.w);
        o[4] = (short)f2bf(w1.x); o[5] = (short)f2bf(w1.y);
        o[6] = (short)f2bf(w1.z); o[7] = (short)f2bf(w1.w);
        *(v8s*)(Wbf + (size_t)g * 8) = o;
    }
}

// ---------------------------------------------------------------------------
// GEMM: out[r][n] = sum_k A[r][k] * W[n][k]  (W stored row-major = B^T form)
// 256x128 block, 4 waves 2(M)x2(N), each wave 128x64 = 8x4 MFMA 16x16x32.
// DOUBLE-BUFFERED K-loop (BK=32, ping-pong LDS, ONE barrier per iter).
// SWIZZLE: chunk ^= (row>>1)&3  [NOT row&3]. With BK=32 the row stride is
// 64 B = 16 banks, so bank-start = (row&1)*16 + c*4; using (row>>1)&3 makes
// (row&1, (row>>1)&3) span 8 distinct 128B-aligned positions over a quad's
// 16 rows -> 2 lanes/bank = conflict-free.  (row&3 collapsed to 4 -> 4-way,
// the R4 regression: SQ_LDS_BANK_CONFLICT 6.29M.)
// OPERAND SWAP: mfma(W_frag, A_frag) -> acc holds out^T; lane's 4 acc regs
// are 4 consecutive output columns at fixed row -> dwordx4 stores.
// ---------------------------------------------------------------------------
__global__ __launch_bounds__(256, 2) void gemm_kernel(
    const unsigned short* __restrict__ Abf,
    const unsigned short* __restrict__ Wbf,
    const float* __restrict__ bt,
    const float* __restrict__ mwz,
    float* __restrict__ out)
{
    // [2 buffers][tile]: A = 256x32, B = 128x32 bf16
    __shared__ __align__(16) unsigned short lA[2][BM * BK];  // 2 x 16 KiB
    __shared__ __align__(16) unsigned short lB[2][BN * BK];  // 2 x  8 KiB

    const int tid  = threadIdx.x;
    const int lane = tid & 63;
    const int wave = tid >> 6;
    const int wr   = wave & 1;        // wave M-half (0..1) -> 128 rows
    const int wc   = wave >> 1;       // wave N-half (0..1) -> 64 cols
    const int quad = lane >> 4;       // 0..3
    const int mcol = lane & 15;       // 0..15

    const int br = blockIdx.x;        // 32 row-blocks
    const int bc = blockIdx.y;        // 16 col-blocks

    v4f acc[8][4];
    const v4f vzero = {0.f, 0.f, 0.f, 0.f};
    #pragma unroll
    for (int i = 0; i < 8; i++)
        #pragma unroll
        for (int j = 0; j < 4; j++) acc[i][j] = vzero;

    const unsigned short* gA = Abf + (size_t)(br * BM) * KDIM;
    const unsigned short* gB = Wbf + (size_t)(bc * BN) * KDIM;

    // stage(kt -> buffer b): A 256x32 (4 issues), B 128x32 (2 issues)
    // LDS slot f: row=f>>2, slot chunk s=f&3 holds global chunk s^((row>>1)&3)
    #define STAGE(KT, BUF)                                                     \
        {                                                                      \
            const int kt_ = (KT);                                              \
            _Pragma("unroll")                                                  \
            for (int q = 0; q < 4; q++) {                                      \
                const int f   = q * 256 + tid;                                 \
                const int row = f >> 2;                                        \
                const int ch  = (f & 3) ^ ((row >> 1) & 3);                    \
                const unsigned short* ga = gA + (size_t)row * KDIM + kt_ + ch * 8; \
                __builtin_amdgcn_global_load_lds(                              \
                    (const __attribute__((address_space(1))) void*)ga,         \
                    (__attribute__((address_space(3))) void*)(&lA[BUF][(size_t)f * 8]), \
                    16, 0, 0);                                                 \
            }                                                                  \
            _Pragma("unroll")                                                  \
            for (int q = 0; q < 2; q++) {                                      \
                const int f   = q * 256 + tid;                                 \
                const int row = f >> 2;                                        \
                const int ch  = (f & 3) ^ ((row >> 1) & 3);                    \
                const unsigned short* gb = gB + (size_t)row * KDIM + kt_ + ch * 8; \
                __builtin_amdgcn_global_load_lds(                              \
                    (const __attribute__((address_space(1))) void*)gb,         \
                    (__attribute__((address_space(3))) void*)(&lB[BUF][(size_t)f * 8]), \
                    16, 0, 0);                                                 \
            }                                                                  \
        }

    STAGE(0, 0);   // prologue: first tile into buffer 0

    const int NITER = KDIM / BK;   // 64
    for (int it = 0; it < NITER; it++) {
        const int cur = it & 1;
        const int nxt = cur ^ 1;

        // barrier: (a) drains this wave's loads into buf_cur (compiler emits
        // vmcnt(0) before s_barrier); (b) all waves done reading buf_nxt from
        // iter it-1, so overwriting it below is safe.
        __syncthreads();

        if (it + 1 < NITER) STAGE((it + 1) * BK, nxt);

        // compute from buf_cur: one K=32 step, 8x4 tiles, 12 ds_read_b128
        v8s af[8], bf_[4];
        #pragma unroll
        for (int i = 0; i < 8; i++) {
            const int row = wr * 128 + i * 16 + mcol;      // A row (m)
            const int c   = quad ^ ((row >> 1) & 3);       // unswizzle
            af[i] = *(const v8s*)(&lA[cur][row * BK + c * 8]);
        }
        #pragma unroll
        for (int j = 0; j < 4; j++) {
            const int col = wc * 64 + j * 16 + mcol;       // B col (n)
            const int c   = quad ^ ((col >> 1) & 3);
            bf_[j] = *(const v8s*)(&lB[cur][col * BK + c * 8]);
        }
        // operand swap: D = W_frag x A_frag => acc is out^T tile:
        //   reg-index (quad*4+r) = output COLUMN, mcol = output ROW
        #pragma unroll
        for (int i = 0; i < 8; i++)
            #pragma unroll
            for (int j = 0; j < 4; j++)
                acc[i][j] = __builtin_amdgcn_mfma_f32_16x16x32_bf16(
                    bf_[j], af[i], acc[i][j], 0, 0, 0);
    }
    #undef STAGE

    // ---- epilogue: bias + relu + scale + relu, dwordx4 fp32 stores ----
    // row parity: all tile offsets even, so parity = mcol & 1
    const float mz = mwz[mcol & 1];
    #pragma unroll
    for (int j = 0; j < 4; j++) {
        const int ncol = bc * BN + wc * 64 + j * 16 + quad * 4;  // 4 consecutive cols
        const float4 b4 = *(const float4*)(bt + ncol);
        #pragma unroll
        for (int i = 0; i < 8; i++) {
            const int row = br * BM + wr * 128 + i * 16 + mcol;
            float4 o;
            o.x = fmaxf(mz * fmaxf(acc[i][j][0] + b4.x, 0.0f), 0.0f);
            o.y = fmaxf(mz * fmaxf(acc[i][j][1] + b4.y, 0.0f), 0.0f);
            o.z = fmaxf(mz * fmaxf(acc[i][j][2] + b4.z, 0.0f), 0.0f);
            o.w = fmaxf(mz * fmaxf(acc[i][j][3] + b4.w, 0.0f), 0.0f);
            *(float4*)(out + (size_t)row * NDIM + ncol) = o;
        }
    }
}

// ---------------------------------------------------------------------------
extern "C" void kernel_launch(void* const* d_in, const int* in_sizes, int n_in,
                              void* d_out, int out_size, void* d_ws, size_t ws_size,
                              hipStream_t stream) {
    const float* x    = (const float*)d_in[0];
    const int*   ids  = (const int*)  d_in[1];
    const float* mw   = (const float*)d_in[2];
    const float* emb  = (const float*)d_in[3];
    const float* Wt   = (const float*)d_in[4];
    const float* bt   = (const float*)d_in[5];
    const float* Wrc  = (const float*)d_in[6];
    const float* brc  = (const float*)d_in[7];
    float* out = (float*)d_out;

    char* ws = (char*)d_ws;
    unsigned short* Abf = (unsigned short*)(ws + A_OFF);
    unsigned short* Wbf = (unsigned short*)(ws + W_OFF);
    float* mwz          = (float*)(ws + MWZ_OFF);

    prep_kernel<<<2048, 256, 0, stream>>>(x, ids, mw, emb, Wrc, brc, Wt,
                                          Abf, Wbf, mwz);

    dim3 grid(MROWS / BM, NDIM / BN);   // 32 x 16 = 512 blocks = 2/CU exactly
    gemm_kernel<<<grid, 256, 0, stream>>>(Abf, Wbf, bt, mwz, out);
}

// Round 6
// 210.737 us; speedup vs baseline: 1.0865x; 1.0814x over previous
//
#include <hip/hip_runtime.h>
#include <hip/hip_bf16.h>
#include <math.h>

// Problem dims (fixed by the reference): B=4096, M=2, D=2048
#define MROWS 8192   // B*M rows of the GEMM
#define KDIM  2048
#define NDIM  2048

#define BM 256
#define BN 128
#define BK 64        // single-buffer: (256+128)*64*2B = 48 KiB LDS

typedef short  v8s  __attribute__((ext_vector_type(8)));   // 8 bf16 (4 VGPRs)
typedef float  v16f __attribute__((ext_vector_type(16)));  // 32x32 MFMA acc

// workspace layout (bytes)
#define A_OFF   0ull
#define W_OFF   ((unsigned long long)MROWS * KDIM * 2ull)               // 32 MiB
#define MWZ_OFF (W_OFF + (unsigned long long)NDIM * KDIM * 2ull)        // +8 MiB

__device__ inline unsigned short f2bf(float f) {
    __hip_bfloat16 h = __float2bfloat16(f);   // RNE
    return *reinterpret_cast<unsigned short*>(&h);
}

// ---------------------------------------------------------------------------
// Prep: zeta scalar, A = bf16(x + emb[ids]), W = bf16(Wt)
// ---------------------------------------------------------------------------
__global__ __launch_bounds__(256) void prep_kernel(
    const float* __restrict__ x, const int* __restrict__ ids,
    const float* __restrict__ mw, const float* __restrict__ emb,
    const float* __restrict__ Wrc, const float* __restrict__ brc,
    const float* __restrict__ Wt,
    unsigned short* __restrict__ Abf, unsigned short* __restrict__ Wbf,
    float* __restrict__ mwz)
{
    const int tid = threadIdx.x;

    // zeta = sigmoid(0.2 * sum(Wrc) + brc); block 0 only
    if (blockIdx.x == 0) {
        __shared__ float red[256];
        float s = 0.f;
        for (int d = tid; d < KDIM; d += 256) s += Wrc[d];
        red[tid] = s;
        __syncthreads();
        for (int off = 128; off > 0; off >>= 1) {
            if (tid < off) red[tid] += red[tid + off];
            __syncthreads();
        }
        if (tid == 0) {
            float zeta = 1.0f / (1.0f + expf(-(0.2f * red[0] + brc[0])));
            mwz[0] = mw[0] * zeta;
            mwz[1] = mw[1] * zeta;
        }
    }

    // A conversion: 8 floats -> 8 bf16 per thread-iter
    const int groupsA = MROWS * KDIM / 8;
    for (int g = blockIdx.x * 256 + tid; g < groupsA; g += gridDim.x * 256) {
        const int row = g >> 8;            // 256 groups of 8 per 2048-row
        const int off = (g & 255) << 3;
        const int st  = ids[row];
        const float4* xp = (const float4*)(x   + (size_t)row * KDIM + off);
        const float4* ep = (const float4*)(emb + (size_t)st  * KDIM + off);
        float4 x0 = xp[0], x1 = xp[1];
        float4 e0 = ep[0], e1 = ep[1];
        v8s o;
        o[0] = (short)f2bf(x0.x + e0.x);
        o[1] = (short)f2bf(x0.y + e0.y);
        o[2] = (short)f2bf(x0.z + e0.z);
        o[3] = (short)f2bf(x0.w + e0.w);
        o[4] = (short)f2bf(x1.x + e1.x);
        o[5] = (short)f2bf(x1.y + e1.y);
        o[6] = (short)f2bf(x1.z + e1.z);
        o[7] = (short)f2bf(x1.w + e1.w);
        *(v8s*)(Abf + (size_t)g * 8) = o;
    }

    // W conversion
    const int groupsW = NDIM * KDIM / 8;
    for (int g = blockIdx.x * 256 + tid; g < groupsW; g += gridDim.x * 256) {
        const float4* wp = (const float4*)(Wt + (size_t)g * 8);
        float4 w0 = wp[0], w1 = wp[1];
        v8s o;
        o[0] = (short)f2bf(w0.x); o[1] = (short)f2bf(w0.y);
        o[2] = (short)f2bf(w0.z); o[3] = (short)f2bf(w0.w);
        o[4] = (short)f2bf(w1.x); o[5] = (short)f2bf(w1.y);
        o[6] = (short)f2bf(w1.z); o[7] = (short)f2bf(w1.w);
        *(v8s*)(Wbf + (size_t)g * 8) = o;
    }
}

// ---------------------------------------------------------------------------
// GEMM: out[r][n] = sum_k A[r][k] * W[n][k]  (W stored row-major = B^T form)
// R3 structure (proven 71us; dbuf regressed in R4/R5 — compiler inserts
// conservative vmcnt(0) before ds_reads that follow in-flight DMA issues).
// 256x128 block, 4 waves 2(M)x2(N), each wave 128x64.
// MFMA 32x32x16 bf16: 4x2 tiles of 32x32 per wave; per BK=64 iter:
// 24 ds_read_b128 + 32 MFMA (vs 64 with 16x16x32) — half the MFMA issues
// at the better 32x32 rate (2382 vs 2075 TF ubench).
// SWIZZLE: fetch-side chunk ^= row&7 (row stride 128 B = 32 banks; frag
// reads land 8 words/bank = b128 minimum -> conflict-free).
// OPERAND SWAP: mfma(W_frag, A_frag) -> acc holds out^T; lane's 16 regs =
// 4 groups of 4 consecutive output cols (n = 8g + 4*(lane>>5) + r) at
// output row = lane&31 -> dwordx4 stores.
// ---------------------------------------------------------------------------
__global__ __launch_bounds__(256, 2) void gemm_kernel(
    const unsigned short* __restrict__ Abf,
    const unsigned short* __restrict__ Wbf,
    const float* __restrict__ bt,
    const float* __restrict__ mwz,
    float* __restrict__ out)
{
    __shared__ __align__(16) unsigned short lA[BM * BK];  // 32 KiB
    __shared__ __align__(16) unsigned short lB[BN * BK];  // 16 KiB

    const int tid  = threadIdx.x;
    const int lane = tid & 63;
    const int wave = tid >> 6;
    const int wr   = wave & 1;        // wave M-half (0..1) -> 128 rows
    const int wc   = wave >> 1;       // wave N-half (0..1) -> 64 cols
    const int l31  = lane & 31;       // row/col within 32x32 tile
    const int kh   = lane >> 5;       // k-half (0..1) within K=16 step

    const int br = blockIdx.x;        // 32 row-blocks
    const int bc = blockIdx.y;        // 16 col-blocks

    v16f acc[4][2];
    #pragma unroll
    for (int i = 0; i < 4; i++)
        #pragma unroll
        for (int j = 0; j < 2; j++)
            #pragma unroll
            for (int r = 0; r < 16; r++) acc[i][j][r] = 0.f;

    const unsigned short* gA = Abf + (size_t)(br * BM) * KDIM;
    const unsigned short* gB = Wbf + (size_t)(bc * BN) * KDIM;

    for (int kt = 0; kt < KDIM; kt += BK) {
        // ---- stage A (256x64) and B (128x64) bf16 tiles: 48 KiB ----
        // LDS slot f holds row=f>>3, global chunk ch = (f&7) ^ (row&7)  (XOR
        // swizzle on the fetch side; global_load_lds dest = base+lane*16)
        #pragma unroll
        for (int q = 0; q < 8; q++) {
            const int f   = q * 256 + tid;
            const int row = f >> 3;
            const int ch  = (f & 7) ^ (row & 7);
            const unsigned short* ga = gA + (size_t)row * KDIM + kt + ch * 8;
            __builtin_amdgcn_global_load_lds(
                (const __attribute__((address_space(1))) void*)ga,
                (__attribute__((address_space(3))) void*)(&lA[(size_t)f * 8]),
                16, 0, 0);
        }
        #pragma unroll
        for (int q = 0; q < 4; q++) {
            const int f   = q * 256 + tid;
            const int row = f >> 3;
            const int ch  = (f & 7) ^ (row & 7);
            const unsigned short* gb = gB + (size_t)row * KDIM + kt + ch * 8;
            __builtin_amdgcn_global_load_lds(
                (const __attribute__((address_space(1))) void*)gb,
                (__attribute__((address_space(3))) void*)(&lB[(size_t)f * 8]),
                16, 0, 0);
        }
        __syncthreads();   // drains vmcnt(0): staging complete

        // ---- compute: 4 k-steps of K=16; per step 6 ds_read + 8 MFMA ----
        #pragma unroll
        for (int ks = 0; ks < BK; ks += 16) {
            const int cc = (ks >> 3) + kh;                 // global k-chunk
            v8s af[4], bf_[2];
            #pragma unroll
            for (int i = 0; i < 4; i++) {
                const int row = wr * 128 + i * 32 + l31;   // A row (m)
                const int c   = cc ^ (row & 7);            // unswizzle
                af[i] = *(const v8s*)(&lA[row * BK + c * 8]);
            }
            #pragma unroll
            for (int j = 0; j < 2; j++) {
                const int col = wc * 64 + j * 32 + l31;    // B col (n)
                const int c   = cc ^ (col & 7);
                bf_[j] = *(const v8s*)(&lB[col * BK + c * 8]);
            }
            // operand swap: D = W_frag x A_frag => acc is out^T tile
            #pragma unroll
            for (int i = 0; i < 4; i++)
                #pragma unroll
                for (int j = 0; j < 2; j++)
                    acc[i][j] = __builtin_amdgcn_mfma_f32_32x32x16_bf16(
                        bf_[j], af[i], acc[i][j], 0, 0, 0);
        }
        __syncthreads();   // protect LDS before next stage overwrites
    }

    // ---- epilogue: bias + relu + scale + relu, dwordx4 fp32 stores ----
    // output row = ... + l31; row parity = lane&1
    const float mz = mwz[lane & 1];
    #pragma unroll
    for (int i = 0; i < 4; i++) {
        const int row = br * BM + wr * 128 + i * 32 + l31;
        #pragma unroll
        for (int j = 0; j < 2; j++) {
            const int ncb = bc * BN + wc * 64 + j * 32 + kh * 4;
            #pragma unroll
            for (int g = 0; g < 4; g++) {
                const int n0 = ncb + g * 8;                // 4 consecutive cols
                const float4 b4 = *(const float4*)(bt + n0);
                float4 o;
                o.x = fmaxf(mz * fmaxf(acc[i][j][g*4+0] + b4.x, 0.0f), 0.0f);
                o.y = fmaxf(mz * fmaxf(acc[i][j][g*4+1] + b4.y, 0.0f), 0.0f);
                o.z = fmaxf(mz * fmaxf(acc[i][j][g*4+2] + b4.z, 0.0f), 0.0f);
                o.w = fmaxf(mz * fmaxf(acc[i][j][g*4+3] + b4.w, 0.0f), 0.0f);
                *(float4*)(out + (size_t)row * NDIM + n0) = o;
            }
        }
    }
}

// ---------------------------------------------------------------------------
extern "C" void kernel_launch(void* const* d_in, const int* in_sizes, int n_in,
                              void* d_out, int out_size, void* d_ws, size_t ws_size,
                              hipStream_t stream) {
    const float* x    = (const float*)d_in[0];
    const int*   ids  = (const int*)  d_in[1];
    const float* mw   = (const float*)d_in[2];
    const float* emb  = (const float*)d_in[3];
    const float* Wt   = (const float*)d_in[4];
    const float* bt   = (const float*)d_in[5];
    const float* Wrc  = (const float*)d_in[6];
    const float* brc  = (const float*)d_in[7];
    float* out = (float*)d_out;

    char* ws = (char*)d_ws;
    unsigned short* Abf = (unsigned short*)(ws + A_OFF);
    unsigned short* Wbf = (unsigned short*)(ws + W_OFF);
    float* mwz          = (float*)(ws + MWZ_OFF);

    prep_kernel<<<2048, 256, 0, stream>>>(x, ids, mw, emb, Wrc, brc, Wt,
                                          Abf, Wbf, mwz);

    dim3 grid(MROWS / BM, NDIM / BN);   // 32 x 16 = 512 blocks = 2/CU exactly
    gemm_kernel<<<grid, 256, 0, stream>>>(Abf, Wbf, bt, mwz, out);
}

// Round 7
// 198.861 us; speedup vs baseline: 1.1514x; 1.0597x over previous
//
#include <hip/hip_runtime.h>
#include <hip/hip_bf16.h>
#include <math.h>

// Problem dims (fixed by the reference): B=4096, M=2, D=2048
#define MROWS 8192   // B*M rows of the GEMM
#define KDIM  2048
#define NDIM  2048

#define BM 256
#define BN 128
#define BK 64        // single-buffer: (256+128)*64*2B = 48 KiB LDS

typedef short  v8s __attribute__((ext_vector_type(8)));   // 8 bf16 (4 VGPRs)
typedef float  v4f __attribute__((ext_vector_type(4)));   // MFMA acc

// workspace layout (bytes)
#define A_OFF   0ull
#define W_OFF   ((unsigned long long)MROWS * KDIM * 2ull)               // 32 MiB
#define MWZ_OFF (W_OFF + (unsigned long long)NDIM * KDIM * 2ull)        // +8 MiB

__device__ inline unsigned short f2bf(float f) {
    __hip_bfloat16 h = __float2bfloat16(f);   // RNE
    return *reinterpret_cast<unsigned short*>(&h);
}

// ---------------------------------------------------------------------------
// Prep: zeta scalar, A = bf16(x + emb[ids]), W = bf16(Wt)
// ---------------------------------------------------------------------------
__global__ __launch_bounds__(256) void prep_kernel(
    const float* __restrict__ x, const int* __restrict__ ids,
    const float* __restrict__ mw, const float* __restrict__ emb,
    const float* __restrict__ Wrc, const float* __restrict__ brc,
    const float* __restrict__ Wt,
    unsigned short* __restrict__ Abf, unsigned short* __restrict__ Wbf,
    float* __restrict__ mwz)
{
    const int tid = threadIdx.x;

    // zeta = sigmoid(0.2 * sum(Wrc) + brc); block 0 only
    if (blockIdx.x == 0) {
        __shared__ float red[256];
        float s = 0.f;
        for (int d = tid; d < KDIM; d += 256) s += Wrc[d];
        red[tid] = s;
        __syncthreads();
        for (int off = 128; off > 0; off >>= 1) {
            if (tid < off) red[tid] += red[tid + off];
            __syncthreads();
        }
        if (tid == 0) {
            float zeta = 1.0f / (1.0f + expf(-(0.2f * red[0] + brc[0])));
            mwz[0] = mw[0] * zeta;
            mwz[1] = mw[1] * zeta;
        }
    }

    // A conversion: 8 floats -> 8 bf16 per thread-iter
    const int groupsA = MROWS * KDIM / 8;
    for (int g = blockIdx.x * 256 + tid; g < groupsA; g += gridDim.x * 256) {
        const int row = g >> 8;            // 256 groups of 8 per 2048-row
        const int off = (g & 255) << 3;
        const int st  = ids[row];
        const float4* xp = (const float4*)(x   + (size_t)row * KDIM + off);
        const float4* ep = (const float4*)(emb + (size_t)st  * KDIM + off);
        float4 x0 = xp[0], x1 = xp[1];
        float4 e0 = ep[0], e1 = ep[1];
        v8s o;
        o[0] = (short)f2bf(x0.x + e0.x);
        o[1] = (short)f2bf(x0.y + e0.y);
        o[2] = (short)f2bf(x0.z + e0.z);
        o[3] = (short)f2bf(x0.w + e0.w);
        o[4] = (short)f2bf(x1.x + e1.x);
        o[5] = (short)f2bf(x1.y + e1.y);
        o[6] = (short)f2bf(x1.z + e1.z);
        o[7] = (short)f2bf(x1.w + e1.w);
        *(v8s*)(Abf + (size_t)g * 8) = o;
    }

    // W conversion
    const int groupsW = NDIM * KDIM / 8;
    for (int g = blockIdx.x * 256 + tid; g < groupsW; g += gridDim.x * 256) {
        const float4* wp = (const float4*)(Wt + (size_t)g * 8);
        float4 w0 = wp[0], w1 = wp[1];
        v8s o;
        o[0] = (short)f2bf(w0.x); o[1] = (short)f2bf(w0.y);
        o[2] = (short)f2bf(w0.z); o[3] = (short)f2bf(w0.w);
        o[4] = (short)f2bf(w1.x); o[5] = (short)f2bf(w1.y);
        o[6] = (short)f2bf(w1.z); o[7] = (short)f2bf(w1.w);
        *(v8s*)(Wbf + (size_t)g * 8) = o;
    }
}

// ---------------------------------------------------------------------------
// GEMM: out[r][n] = sum_k A[r][k] * W[n][k]  (W stored row-major = B^T form)
// 256x128 block, 4 waves in 2(M)x2(N); each wave owns a 128x64 tile =
// 8x4 of 16x16x32 bf16 MFMA. 512 blocks = exactly 2/CU x 256 CU -> no tail.
// This is the proven best structure (R3: 71.4us, 962 TF, 0 bank conflicts).
// R4/R5 (explicit dbuf) and R6 (32x32 MFMA) all regressed:
//  - dbuf: compiler inserts conservative vmcnt(0) before ds_reads that
//    follow in-flight global_load_lds to the other buffer -> serializes.
//  - 32x32: fragment reads touch rows in 32-B segments (2 lanes/row) vs
//    this layout's contiguous 64-B half-rows (4 quads/row) -> +4cyc/ds_read
//    (SQ_LDS_BANK_CONFLICT 6.29M).
// SWIZZLE: fetch-side chunk ^= row&7; quad reads {cc..cc+3}^(row&7) = a
// contiguous 64-B half-row per 4 lanes -> conflict-free.
// OPERAND SWAP: mfma(W_frag, A_frag) -> acc holds out^T; lane's 4 acc regs
// are 4 consecutive output columns at fixed row -> dwordx4 stores.
// Epilogue: relu(mwz[row&1] * relu(acc + bt[n]))
// ---------------------------------------------------------------------------
__global__ __launch_bounds__(256, 2) void gemm_kernel(
    const unsigned short* __restrict__ Abf,
    const unsigned short* __restrict__ Wbf,
    const float* __restrict__ bt,
    const float* __restrict__ mwz,
    float* __restrict__ out)
{
    __shared__ __align__(16) unsigned short lA[BM * BK];  // 32 KiB
    __shared__ __align__(16) unsigned short lB[BN * BK];  // 16 KiB

    const int tid  = threadIdx.x;
    const int lane = tid & 63;
    const int wave = tid >> 6;
    const int wr   = wave & 1;        // wave M-half (0..1) -> 128 rows
    const int wc   = wave >> 1;       // wave N-half (0..1) -> 64 cols
    const int quad = lane >> 4;       // 0..3
    const int mcol = lane & 15;       // 0..15

    const int br = blockIdx.x;        // 32 row-blocks
    const int bc = blockIdx.y;        // 16 col-blocks

    v4f acc[8][4];
    const v4f vzero = {0.f, 0.f, 0.f, 0.f};
    #pragma unroll
    for (int i = 0; i < 8; i++)
        #pragma unroll
        for (int j = 0; j < 4; j++) acc[i][j] = vzero;

    const unsigned short* gA = Abf + (size_t)(br * BM) * KDIM;
    const unsigned short* gB = Wbf + (size_t)(bc * BN) * KDIM;

    for (int kt = 0; kt < KDIM; kt += BK) {
        // ---- stage A (256x64) and B (128x64) bf16 tiles: 48 KiB ----
        // LDS slot f holds row=f>>3, global chunk ch = (f&7) ^ (row&7)  (XOR
        // swizzle applied on the fetch side; LDS dest is forced base+lane*16)
        #pragma unroll
        for (int q = 0; q < 8; q++) {
            const int f   = q * 256 + tid;
            const int row = f >> 3;
            const int ch  = (f & 7) ^ (row & 7);
            const unsigned short* ga = gA + (size_t)row * KDIM + kt + ch * 8;
            __builtin_amdgcn_global_load_lds(
                (const __attribute__((address_space(1))) void*)ga,
                (__attribute__((address_space(3))) void*)(&lA[(size_t)f * 8]),
                16, 0, 0);
        }
        #pragma unroll
        for (int q = 0; q < 4; q++) {
            const int f   = q * 256 + tid;
            const int row = f >> 3;
            const int ch  = (f & 7) ^ (row & 7);
            const unsigned short* gb = gB + (size_t)row * KDIM + kt + ch * 8;
            __builtin_amdgcn_global_load_lds(
                (const __attribute__((address_space(1))) void*)gb,
                (__attribute__((address_space(3))) void*)(&lB[(size_t)f * 8]),
                16, 0, 0);
        }
        __syncthreads();   // drains vmcnt(0): staging complete

        // ---- compute: 2 k-steps of 16x16x32, 8x4 tiles per wave ----
        #pragma unroll
        for (int ks = 0; ks < BK; ks += 32) {
            v8s af[8], bf_[4];
            #pragma unroll
            for (int i = 0; i < 8; i++) {
                const int row = wr * 128 + i * 16 + mcol;      // A row (m)
                const int cc  = (ks >> 3) + quad;              // k-chunk
                const int c   = cc ^ (row & 7);                // unswizzle
                af[i] = *(const v8s*)(&lA[row * BK + c * 8]);
            }
            #pragma unroll
            for (int j = 0; j < 4; j++) {
                const int col = wc * 64 + j * 16 + mcol;       // B col (n)
                const int cc  = (ks >> 3) + quad;
                const int c   = cc ^ (col & 7);
                bf_[j] = *(const v8s*)(&lB[col * BK + c * 8]);
            }
            // operand swap: D = W_frag x A_frag  => acc[i][j] is out^T tile:
            //   reg-index (quad*4+r) = output COLUMN, mcol = output ROW
            #pragma unroll
            for (int i = 0; i < 8; i++)
                #pragma unroll
                for (int j = 0; j < 4; j++)
                    acc[i][j] = __builtin_amdgcn_mfma_f32_16x16x32_bf16(
                        bf_[j], af[i], acc[i][j], 0, 0, 0);
        }
        __syncthreads();   // protect LDS before next stage overwrites
    }

    // ---- epilogue: bias + relu + scale + relu, dwordx4 fp32 stores ----
    // row parity: all tile offsets even, so parity = mcol & 1
    const float mz = mwz[mcol & 1];
    #pragma unroll
    for (int j = 0; j < 4; j++) {
        const int ncol = bc * BN + wc * 64 + j * 16 + quad * 4;  // 4 consecutive cols
        const float4 b4 = *(const float4*)(bt + ncol);
        #pragma unroll
        for (int i = 0; i < 8; i++) {
            const int row = br * BM + wr * 128 + i * 16 + mcol;
            float4 o;
            o.x = fmaxf(mz * fmaxf(acc[i][j][0] + b4.x, 0.0f), 0.0f);
            o.y = fmaxf(mz * fmaxf(acc[i][j][1] + b4.y, 0.0f), 0.0f);
            o.z = fmaxf(mz * fmaxf(acc[i][j][2] + b4.z, 0.0f), 0.0f);
            o.w = fmaxf(mz * fmaxf(acc[i][j][3] + b4.w, 0.0f), 0.0f);
            *(float4*)(out + (size_t)row * NDIM + ncol) = o;
        }
    }
}

// ---------------------------------------------------------------------------
extern "C" void kernel_launch(void* const* d_in, const int* in_sizes, int n_in,
                              void* d_out, int out_size, void* d_ws, size_t ws_size,
                              hipStream_t stream) {
    const float* x    = (const float*)d_in[0];
    const int*   ids  = (const int*)  d_in[1];
    const float* mw   = (const float*)d_in[2];
    const float* emb  = (const float*)d_in[3];
    const float* Wt   = (const float*)d_in[4];
    const float* bt   = (const float*)d_in[5];
    const float* Wrc  = (const float*)d_in[6];
    const float* brc  = (const float*)d_in[7];
    float* out = (float*)d_out;

    char* ws = (char*)d_ws;
    unsigned short* Abf = (unsigned short*)(ws + A_OFF);
    unsigned short* Wbf = (unsigned short*)(ws + W_OFF);
    float* mwz          = (float*)(ws + MWZ_OFF);

    prep_kernel<<<2048, 256, 0, stream>>>(x, ids, mw, emb, Wrc, brc, Wt,
                                          Abf, Wbf, mwz);

    dim3 grid(MROWS / BM, NDIM / BN);   // 32 x 16 = 512 blocks = 2/CU exactly
    gemm_kernel<<<grid, 256, 0, stream>>>(Abf, Wbf, bt, mwz, out);
}